// Round 5
// baseline (116.777 us; speedup 1.0000x reference)
//
#include <hip/hip_runtime.h>
#include <math.h>

// NT-Xent (SimCLR) loss. B=4096, D=256, T=0.5.
// zb = bf16( SCALE * normalize(concat(emb_i, emb_j)) ), SCALE = sqrt(2*log2 e)
//   => acc = zb@zb^T = 2*log2(e)*sim, so exp(2*sim) == exp2(acc) (1 transcendental).
// Upper-triangle 128x128 tiles only (exp matrix symmetric): tile (bx,by),
// bx<=by: rowsums -> denomP[by][rows bx], colsums -> denomP[bx][cols by].
// Global diagonal skipped by predicate. pos extracted from by==bx+32 tiles.
// LDS layout is FRAGMENT-ORDERED: each MFMA fragment is a contiguous 1024B
// region [wr][i][kstep][lane*16B] -> ds_read_b128 is lane-contiguous
// (conflict-free), while global_load_lds staging stays 64B-segment coalesced.
// loss = (1/8192) * ( (4/2.88539)*sum_k posacc[k] - sum_r log(denom[r]) )

#define NROWS 8192
#define NHALF 4096
#define DIM   256
#define BM    128
#define BN    128
#define BK    64
#define NCB   (NROWS / BN)          // 64 row/col blocks
#define NTRI  (NCB * (NCB + 1) / 2) // 2080 triangle tiles

#define SCALE    1.69864344f   // sqrt(2*log2(e))
#define POSMUL   1.38629436f   // 4 / (2*log2(e)) = 2*ln2

typedef __attribute__((ext_vector_type(8))) short bf16x8;
typedef __attribute__((ext_vector_type(4))) float f32x4;

#if __has_builtin(__builtin_amdgcn_exp2f)
#define EXP2(x) __builtin_amdgcn_exp2f(x)
#else
#define EXP2(x) __expf((x) * 0.69314718f)
#endif

static __device__ __forceinline__ unsigned short f2bf(float x) {
  unsigned int u = __float_as_uint(x);
  unsigned int r = (u + 0x7FFFu + ((u >> 16) & 1u)) >> 16;
  return (unsigned short)r;
}

// ------------------------------------------- normalize (also zeroes out[0])
__global__ __launch_bounds__(256) void normalize_kernel(
    const float* __restrict__ emb_i, const float* __restrict__ emb_j,
    unsigned short* __restrict__ zb, float* __restrict__ out) {
  if (blockIdx.x == 0 && threadIdx.x == 0) out[0] = 0.f;
  int w = threadIdx.x >> 6, lane = threadIdx.x & 63;
  int row = blockIdx.x * 4 + w;
  const float* src = (row < NHALF) ? (emb_i + (size_t)row * DIM)
                                   : (emb_j + (size_t)(row - NHALF) * DIM);
  float4 v = ((const float4*)src)[lane];
  float ss = v.x * v.x + v.y * v.y + v.z * v.z + v.w * v.w;
  #pragma unroll
  for (int off = 32; off; off >>= 1) ss += __shfl_down(ss, off, 64);
  float total = __shfl(ss, 0, 64);
  float inv = SCALE / fmaxf(sqrtf(total), 1e-12f);
  ushort4 o;
  o.x = f2bf(v.x * inv); o.y = f2bf(v.y * inv);
  o.z = f2bf(v.z * inv); o.w = f2bf(v.w * inv);
  ((ushort4*)&zb[(size_t)row * DIM])[lane] = o;
}

// ------------------------------------------------ MFMA GEMM + exp2 + sums
__global__ __launch_bounds__(256) void denom_kernel(
    const unsigned short* __restrict__ zb, float* __restrict__ denomP,
    float* __restrict__ posv) {
  // 16 fragment regions x 512 shorts (1024 B) each, per operand.
  __shared__ __attribute__((aligned(16))) unsigned short As[16 * 512];
  __shared__ __attribute__((aligned(16))) unsigned short Bs[16 * 512];

  // decode triangle tile id -> (bx, by), bx <= by
  int t = blockIdx.x;
  int by = (int)((sqrtf(8.0f * (float)t + 1.0f) - 1.0f) * 0.5f);
  while ((by + 1) * (by + 2) / 2 <= t) ++by;
  while (by * (by + 1) / 2 > t) --by;
  int bx = t - by * (by + 1) / 2;

  const int tid = threadIdx.x;
  const int w = tid >> 6;
  const int lane = tid & 63;
  const int wr = w >> 1, wc = w & 1;  // 2x2 wave grid, 64x64 each
  const int quad = lane >> 4;
  const int m16 = lane & 15;
  const int row0 = bx * BM;
  const int col0 = by * BN;

  f32x4 acc[4][4];
  #pragma unroll
  for (int i = 0; i < 4; ++i)
    #pragma unroll
    for (int j = 0; j < 4; ++j) {
      f32x4 z4 = {0.f, 0.f, 0.f, 0.f};
      acc[i][j] = z4;
    }

  // staging source indices (region ra handled by this wave: ra = w*4+t)
  // region ra = wr_s*8 + i_s*2 + kstep: rows (ra>>1)*16 + m16,
  //                                     k = (ra&1)*32 + quad*8
  for (int kc = 0; kc < DIM; kc += BK) {
    #pragma unroll
    for (int t4 = 0; t4 < 4; ++t4) {
      int ra = w * 4 + t4;
      int grow = (ra >> 1) * 16 + m16;
      int gk = kc + (ra & 1) * 32 + quad * 8;
      __builtin_amdgcn_global_load_lds(
          (const __attribute__((address_space(1))) unsigned int*)
              &zb[(size_t)(row0 + grow) * DIM + gk],
          (__attribute__((address_space(3))) unsigned int*)&As[ra * 512],
          16, 0, 0);
      __builtin_amdgcn_global_load_lds(
          (const __attribute__((address_space(1))) unsigned int*)
              &zb[(size_t)(col0 + grow) * DIM + gk],
          (__attribute__((address_space(3))) unsigned int*)&Bs[ra * 512],
          16, 0, 0);
    }
    __syncthreads();

    #pragma unroll
    for (int ks = 0; ks < BK; ks += 32) {
      const int kst = ks >> 5;
      bf16x8 af[4], bfr[4];
      #pragma unroll
      for (int i = 0; i < 4; ++i)
        af[i] = *(const bf16x8*)&As[(wr * 8 + i * 2 + kst) * 512 + lane * 8];
      #pragma unroll
      for (int j = 0; j < 4; ++j)
        bfr[j] = *(const bf16x8*)&Bs[(wc * 8 + j * 2 + kst) * 512 + lane * 8];
      #pragma unroll
      for (int i = 0; i < 4; ++i)
        #pragma unroll
        for (int j = 0; j < 4; ++j)
          acc[i][j] = __builtin_amdgcn_mfma_f32_16x16x32_bf16(
              af[i], bfr[j], acc[i][j], 0, 0, 0);
    }
    __syncthreads();
  }

  // pos extraction: tiles with col0 == row0 + NHALF hold pair elements
  // (posv stores the SCALED product acc = 2*log2(e)*sim).
  if (col0 - row0 == NHALF) {
    #pragma unroll
    for (int i = 0; i < 4; ++i)
      #pragma unroll
      for (int j = 0; j < 4; ++j) {
        int gcol = col0 + wc * 64 + j * 16 + m16;
        #pragma unroll
        for (int r = 0; r < 4; ++r) {
          int grow = row0 + wr * 64 + i * 16 + quad * 4 + r;
          if (gcol - grow == NHALF) posv[grow] = acc[i][j][r];
        }
      }
  }

  // Epilogue: e = exp2(acc) = exp(2*sim); skip global diagonal; row+col sums.
  // C layout (16x16x32): col = wc*64 + j*16 + m16, row = wr*64+i*16+quad*4+r.
  float rs[4][4];
  float cs[4] = {0.f, 0.f, 0.f, 0.f};
  #pragma unroll
  for (int i = 0; i < 4; ++i)
    #pragma unroll
    for (int r = 0; r < 4; ++r) rs[i][r] = 0.f;

  #pragma unroll
  for (int i = 0; i < 4; ++i)
    #pragma unroll
    for (int j = 0; j < 4; ++j) {
      int gcol = col0 + wc * 64 + j * 16 + m16;
      #pragma unroll
      for (int r = 0; r < 4; ++r) {
        int grow = row0 + wr * 64 + i * 16 + quad * 4 + r;
        float e = (grow == gcol) ? 0.f : EXP2(acc[i][j][r]);
        rs[i][r] += e;
        cs[j] += e;
      }
    }

  float* red = (float*)As;  // 512 floats: [0,256) rowsums, [256,512) colsums

  // rowsum: reduce across the 16 column lanes (same quad)
  #pragma unroll
  for (int i = 0; i < 4; ++i)
    #pragma unroll
    for (int r = 0; r < 4; ++r) {
      float v = rs[i][r];
      v += __shfl_xor(v, 1, 16);
      v += __shfl_xor(v, 2, 16);
      v += __shfl_xor(v, 4, 16);
      v += __shfl_xor(v, 8, 16);
      if (m16 == 0) red[wc * 128 + wr * 64 + i * 16 + quad * 4 + r] = v;
    }
  // colsum: reduce across the 4 quads
  #pragma unroll
  for (int j = 0; j < 4; ++j) {
    float v = cs[j];
    v += __shfl_xor(v, 16, 64);
    v += __shfl_xor(v, 32, 64);
    if (quad == 0) red[256 + wr * 128 + wc * 64 + j * 16 + m16] = v;
  }
  __syncthreads();

  if (tid < 128) {
    denomP[(size_t)by * NROWS + row0 + tid] = red[tid] + red[128 + tid];
  } else if (bx != by) {
    int c = tid - 128;
    denomP[(size_t)bx * NROWS + col0 + c] = red[256 + c] + red[384 + c];
  }
}

// -------------------- denom slots -> -log; + pos term; atomic into loss
__global__ __launch_bounds__(256) void reduce_kernel(
    const float* __restrict__ denomP, const float* __restrict__ posv,
    float* __restrict__ out) {
  int tid = threadIdx.x;
  int r = blockIdx.x * 256 + tid;  // 32 blocks cover 8192 rows
  float s = 0.f;
  #pragma unroll 8
  for (int b = 0; b < NCB; ++b) s += denomP[(size_t)b * NROWS + r];
  float v = -logf(s);
  if (r < NHALF) v += POSMUL * posv[r];
  #pragma unroll
  for (int off = 32; off; off >>= 1) v += __shfl_down(v, off, 64);
  __shared__ float s4[4];
  if ((tid & 63) == 0) s4[tid >> 6] = v;
  __syncthreads();
  if (tid == 0)
    atomicAdd(out, (s4[0] + s4[1] + s4[2] + s4[3]) * (1.0f / 8192.0f));
}

extern "C" void kernel_launch(void* const* d_in, const int* in_sizes, int n_in,
                              void* d_out, int out_size, void* d_ws,
                              size_t ws_size, hipStream_t stream) {
  const float* emb_i = (const float*)d_in[0];
  const float* emb_j = (const float*)d_in[1];
  unsigned short* zb = (unsigned short*)d_ws;            // 4 MB
  float* denomP = (float*)(zb + (size_t)NROWS * DIM);    // 64*8192 f32 (2 MB)
  float* posv = denomP + (size_t)NCB * NROWS;            // 4096 f32
  float* out = (float*)d_out;

  normalize_kernel<<<NROWS / 4, 256, 0, stream>>>(emb_i, emb_j, zb, out);
  denom_kernel<<<NTRI, 256, 0, stream>>>(zb, denomP, posv);
  reduce_kernel<<<NROWS / 256, 256, 0, stream>>>(denomP, posv, out);
}